// Round 1
// 450.718 us; speedup vs baseline: 1.0069x; 1.0069x over previous
//
#include <hip/hip_runtime.h>

// Problem: B=2, G=8, N=4096, D=1024, H=16. kv_len==1 => softmax==1 => attention
// collapses to: o[bg,:] = Wout @ (Wv @ g[bg] + bv) + bout  (independent of n),
// y = rmsnorm(x + o[bg]) * norm_w.
//
// Dtype forensics (from earlier rounds):
//  R1: all-bf16 interpretation -> absmax NaN  => inputs are fp32.
//  R2: fp32-in / bf16-out      -> absmax 8.31 fingerprint => OUTPUT IS FP32.
//
// Timing model (this session, R0): top-5 rocprof dispatches are all 1-GiB
// fillBufferAligned poisons at ~165 us / 6.4 TB/s. 453.8 us total - 2x166 us
// poison ~= 122 us ~= gemv(2x~7) + rmsnorm(~100) + launch slop. The kernels
// appear to already sit near the HBM roofline; this round pushes rmsnorm
// toward the 6.3 TB/s copy ceiling (NT streams + reg-hoisted norm_w +
// grid-stride persistent blocks) to confirm.

#define DM 1024
#define BGC 16        // B*G
#define NROWS 65536   // B*G*N
#define EPS 1e-6f

typedef float vf4 __attribute__((ext_vector_type(4)));

// ---------------- generic GEMV: out[bg,d] = W[row_off+d,:] . in[bg,:] + b[row_off+d]
// One wave per (bg,d). Lanes stride along k: 4 float4 segments, fully coalesced.
// W rows are L2/L3-resident after first bg; ~5-8 us per launch.
__global__ __launch_bounds__(256) void gemv_k(
        const float* __restrict__ W, const float* __restrict__ b,
        const float* __restrict__ in, float* __restrict__ out, int row_off) {
    const int lane = threadIdx.x & 63;
    const int wave = threadIdx.x >> 6;
    const int id   = blockIdx.x * 4 + wave;      // 0 .. BGC*DM-1
    const int bg   = id >> 10;
    const int d    = id & (DM - 1);
    const float* wr = W + (size_t)(row_off + d) * DM;
    const float* ir = in + (size_t)bg * DM;
    float acc = 0.f;
    #pragma unroll
    for (int s = 0; s < 4; ++s) {
        const int k = s * 256 + lane * 4;
        float4 wv = *reinterpret_cast<const float4*>(wr + k);
        float4 iv = *reinterpret_cast<const float4*>(ir + k);
        acc = fmaf(wv.x, iv.x, acc);
        acc = fmaf(wv.y, iv.y, acc);
        acc = fmaf(wv.z, iv.z, acc);
        acc = fmaf(wv.w, iv.w, acc);
    }
    #pragma unroll
    for (int off = 32; off > 0; off >>= 1) acc += __shfl_xor(acc, off, 64);
    if (lane == 0) out[(size_t)bg * DM + d] = acc + b[row_off + d];
}

// ---------------- fused epilogue: y = rmsnorm(x + o[bg]) * norm_w ----------------
// Persistent grid-stride form: 2048 blocks x 4 waves = 8192 waves, 8 rows/wave.
// x is a pure stream-in, y a pure stream-out => non-temporal (keep L2 for o/nw/W).
// norm_w hoisted into registers once per wave (reused across all 8 rows).
// Per-instruction coalescing: 64 lanes x 16B = 1 KiB contiguous per float4 op.
__global__ __launch_bounds__(256) void fused_rmsnorm(
        const float* __restrict__ x, const float* __restrict__ o,
        const float* __restrict__ nw, float* __restrict__ y) {
    const int lane = threadIdx.x & 63;
    const int wave = threadIdx.x >> 6;
    const int wid  = blockIdx.x * 4 + wave;      // 0 .. 8191

    // norm_w: 16 floats per lane, loaded once, reused for all rows.
    vf4 wv[4];
    #pragma unroll
    for (int s = 0; s < 4; ++s)
        wv[s] = *reinterpret_cast<const vf4*>(nw + s * 256 + lane * 4);

    for (long long row = wid; row < NROWS; row += 8192) {
        const int bg = (int)(row >> 12);         // N = 4096
        const float* xr = x + row * DM;
        const float* ob = o + (size_t)bg * DM;
        float*       yr = y + row * DM;

        float t[16];
        #pragma unroll
        for (int s = 0; s < 4; ++s) {
            const int k = s * 256 + lane * 4;
            vf4 xv = __builtin_nontemporal_load(reinterpret_cast<const vf4*>(xr + k));
            vf4 ov = *reinterpret_cast<const vf4*>(ob + k);   // L2-hit broadcast
            t[s * 4 + 0] = xv.x + ov.x;
            t[s * 4 + 1] = xv.y + ov.y;
            t[s * 4 + 2] = xv.z + ov.z;
            t[s * 4 + 3] = xv.w + ov.w;
        }

        float ss = 0.f;
        #pragma unroll
        for (int i = 0; i < 16; ++i) ss = fmaf(t[i], t[i], ss);
        #pragma unroll
        for (int off = 32; off > 0; off >>= 1) ss += __shfl_xor(ss, off, 64);

        const float inv = rsqrtf(ss * (1.0f / 1024.0f) + EPS);

        #pragma unroll
        for (int s = 0; s < 4; ++s) {
            const int k = s * 256 + lane * 4;
            vf4 yo;
            yo.x = t[s * 4 + 0] * inv * wv[s].x;
            yo.y = t[s * 4 + 1] * inv * wv[s].y;
            yo.z = t[s * 4 + 2] * inv * wv[s].z;
            yo.w = t[s * 4 + 3] * inv * wv[s].w;
            __builtin_nontemporal_store(yo, reinterpret_cast<vf4*>(yr + k));
        }
    }
}

extern "C" void kernel_launch(void* const* d_in, const int* in_sizes, int n_in,
                              void* d_out, int out_size, void* d_ws, size_t ws_size,
                              hipStream_t stream) {
    const float* x          = (const float*)d_in[0];
    const float* guidance   = (const float*)d_in[1];
    const float* in_proj_w  = (const float*)d_in[2];
    const float* in_proj_b  = (const float*)d_in[3];
    const float* out_proj_w = (const float*)d_in[4];
    const float* out_proj_b = (const float*)d_in[5];
    const float* norm_w     = (const float*)d_in[6];
    float* y = (float*)d_out;

    float* v = (float*)d_ws;                 // 16*1024 fp32 = 64 KB
    float* o = v + (size_t)BGC * DM;         // next 64 KB

    // v[bg] = Wv @ g[bg] + bv   (Wv = rows [2048,3072) of in_proj_w)
    gemv_k<<<BGC * DM / 4, 256, 0, stream>>>(in_proj_w, in_proj_b, guidance, v, 2048);
    // o[bg] = Wout @ v[bg] + bout
    gemv_k<<<BGC * DM / 4, 256, 0, stream>>>(out_proj_w, out_proj_b, v, o, 0);
    // y = rmsnorm(x + o[bg]) * norm_w
    fused_rmsnorm<<<2048, 256, 0, stream>>>(x, o, norm_w, y);
}